// Round 1
// baseline (3179.877 us; speedup 1.0000x reference)
//
#include <hip/hip_runtime.h>
#include <cstdint>
#include <cstddef>

#define NN 50000
#define NE 800000
#define FIN 128
#define HID 256
#define NCLS 10
#define NG 64

static inline size_t align_up(size_t v, size_t a) { return (v + a - 1) / a * a; }

// ---------------- graph preprocessing ----------------

__global__ void k_degcnt(const int* __restrict__ src, const int* __restrict__ dst,
                         float* __restrict__ deg, int* __restrict__ cnt) {
    int e = blockIdx.x * 256 + threadIdx.x;
    if (e < NE) {
        atomicAdd(&deg[src[e]], 1.0f);
        atomicAdd(&cnt[dst[e]], 1);
    }
}

__global__ void k_dis(const float* __restrict__ deg, float* __restrict__ dis) {
    int n = blockIdx.x * 256 + threadIdx.x;
    if (n < NN) {
        float d = deg[n];
        dis[n] = (d > 0.0f) ? rsqrtf(d) : 0.0f;
    }
}

// single-block exclusive scan of cnt[0..NN) -> row_ptr, cursor; row_ptr[NN]=NE
__global__ void k_scan(const int* __restrict__ cnt, int* __restrict__ row_ptr,
                       int* __restrict__ cursor) {
    __shared__ int s[1024];
    __shared__ int carry;
    if (threadIdx.x == 0) carry = 0;
    __syncthreads();
    for (int base = 0; base < NN; base += 1024) {
        int i = base + threadIdx.x;
        int v = (i < NN) ? cnt[i] : 0;
        s[threadIdx.x] = v;
        __syncthreads();
        for (int off = 1; off < 1024; off <<= 1) {
            int t = (threadIdx.x >= (unsigned)off) ? s[threadIdx.x - off] : 0;
            __syncthreads();
            s[threadIdx.x] += t;
            __syncthreads();
        }
        int excl = s[threadIdx.x] - v;
        int c = carry;  // all threads read carry before it is updated
        if (i < NN) { row_ptr[i] = c + excl; cursor[i] = c + excl; }
        __syncthreads();
        if (threadIdx.x == 0) carry = c + s[1023];
        __syncthreads();
    }
    if (threadIdx.x == 0) row_ptr[NN] = carry;
}

__global__ void k_fill(const int* __restrict__ src, const int* __restrict__ dst,
                       const float* __restrict__ dis, int* __restrict__ cursor,
                       int* __restrict__ col, float* __restrict__ wcsr) {
    int e = blockIdx.x * 256 + threadIdx.x;
    if (e < NE) {
        int s_ = src[e], d_ = dst[e];
        int pos = atomicAdd(&cursor[d_], 1);
        col[pos] = s_;
        wcsr[pos] = -dis[s_] * dis[d_];
    }
}

// ---------------- sparse propagation (CSR by dst) ----------------
// FUSE=0: out[d][f] = sum_e w*h[src][f]
// FUSE=1: out[d][f] = 2*sum_e w*h[src][f] - sub[d][f]   (out==sub is safe)
template <int FUSE>
__global__ void k_prop(const int* __restrict__ row_ptr, const int* __restrict__ col,
                       const float* __restrict__ w, const float* __restrict__ h,
                       const float* __restrict__ sub, float* __restrict__ out, int F) {
    int d = blockIdx.x;
    int f = threadIdx.x;  // blockDim.x == F
    int beg = row_ptr[d], end = row_ptr[d + 1];
    float acc = 0.0f;
    for (int e = beg; e < end; ++e) {
        int s = col[e];
        float wv = w[e];
        acc += wv * h[(size_t)s * F + f];
    }
    size_t o = (size_t)d * F + f;
    if (FUSE) {
        out[o] = 2.0f * acc - sub[o];
    } else {
        out[o] = acc;
    }
}

// ---------------- dense matmul: C (+)= A[MxK] @ W[KxNc] ----------------
// ACCUM: read-modify-write C.  FINAL: add bias and relu.
template <int ACCUM, int FINAL>
__global__ void k_mm(const float* __restrict__ A, const float* __restrict__ W,
                     const float* __restrict__ bias, float* __restrict__ C,
                     int M, int K, int Nc) {
    __shared__ float As[16][65];
    __shared__ float Ws[16][65];
    int tx = threadIdx.x & 15, ty = threadIdx.x >> 4;
    int rowBase = blockIdx.x * 64, colBase = blockIdx.y * 64;
    float acc[4][4] = {};
    for (int k0 = 0; k0 < K; k0 += 16) {
#pragma unroll
        for (int i = 0; i < 4; ++i) {
            int idx = threadIdx.x + 256 * i;  // 0..1023
            int m = idx >> 4, kk = idx & 15;
            int r = rowBase + m;
            As[kk][m] = (r < M) ? A[(size_t)r * K + k0 + kk] : 0.0f;
        }
#pragma unroll
        for (int i = 0; i < 4; ++i) {
            int idx = threadIdx.x + 256 * i;
            int n = idx & 63, kk = idx >> 6;
            Ws[kk][n] = W[(size_t)(k0 + kk) * Nc + colBase + n];
        }
        __syncthreads();
#pragma unroll
        for (int kk = 0; kk < 16; ++kk) {
            float a[4], b[4];
#pragma unroll
            for (int i = 0; i < 4; ++i) a[i] = As[kk][ty * 4 + i];
#pragma unroll
            for (int j = 0; j < 4; ++j) b[j] = Ws[kk][tx * 4 + j];
#pragma unroll
            for (int i = 0; i < 4; ++i)
#pragma unroll
                for (int j = 0; j < 4; ++j) acc[i][j] += a[i] * b[j];
        }
        __syncthreads();
    }
#pragma unroll
    for (int i = 0; i < 4; ++i) {
        int r = rowBase + ty * 4 + i;
        if (r >= M) continue;
#pragma unroll
        for (int j = 0; j < 4; ++j) {
            int c = colBase + tx * 4 + j;
            size_t o = (size_t)r * Nc + c;
            float v = acc[i][j];
            if (ACCUM) v += C[o];
            if (FINAL) { v += bias[c]; v = fmaxf(v, 0.0f); }
            C[o] = v;
        }
    }
}

// ---------------- pooling ----------------

__global__ void k_pool(const float* __restrict__ h, const int* __restrict__ batch,
                       float* __restrict__ sums, float* __restrict__ cnts) {
    int f = threadIdx.x;  // 256
    int n0 = blockIdx.x * 128;
    if (n0 >= NN) return;
    int nEnd = n0 + 128 < NN ? n0 + 128 : NN;
    int cur = batch[n0];
    float acc = 0.0f, c = 0.0f;
    for (int n = n0; n < nEnd; ++n) {
        int b = batch[n];
        if (b != cur) {
            atomicAdd(&sums[cur * HID + f], acc);
            if (f == 0) atomicAdd(&cnts[cur], c);
            acc = 0.0f; c = 0.0f; cur = b;
        }
        acc += h[(size_t)n * HID + f];
        c += 1.0f;
    }
    atomicAdd(&sums[cur * HID + f], acc);
    if (f == 0) atomicAdd(&cnts[cur], c);
}

__global__ void k_gdiv(const float* __restrict__ sums, const float* __restrict__ cnts,
                       float* __restrict__ g) {
    int i = blockIdx.x * 256 + threadIdx.x;  // NG*HID
    int b = i >> 8;
    g[i] = sums[i] / fmaxf(cnts[b], 1.0f);
}

// ---------------- MLP ----------------

template <int RELU>
__global__ void k_fc(const float* __restrict__ in, const float* __restrict__ W,
                     const float* __restrict__ bias, float* __restrict__ out,
                     int K, int Nc) {
    __shared__ float s[512];
    int gi = blockIdx.x;
    for (int i = threadIdx.x; i < K; i += blockDim.x) s[i] = in[gi * K + i];
    __syncthreads();
    int c = blockIdx.y * blockDim.x + threadIdx.x;
    if (c < Nc) {
        float acc = bias[c];
        for (int k = 0; k < K; ++k) acc += s[k] * W[k * Nc + c];
        out[gi * Nc + c] = RELU ? fmaxf(acc, 0.0f) : acc;
    }
}

__global__ void k_fc3_lsm(const float* __restrict__ in, const float* __restrict__ W,
                          const float* __restrict__ b, float* __restrict__ out) {
    __shared__ float s[HID];
    __shared__ float lg[NCLS];
    int gi = blockIdx.x;
    s[threadIdx.x] = in[gi * HID + threadIdx.x];  // blockDim=256
    __syncthreads();
    if (threadIdx.x < NCLS) {
        float acc = b[threadIdx.x];
        for (int k = 0; k < HID; ++k) acc += s[k] * W[k * NCLS + threadIdx.x];
        lg[threadIdx.x] = acc;
    }
    __syncthreads();
    if (threadIdx.x < NCLS) {
        float m = -1e30f;
        for (int c = 0; c < NCLS; ++c) m = fmaxf(m, lg[c]);
        float sum = 0.0f;
        for (int c = 0; c < NCLS; ++c) sum += expf(lg[c] - m);
        out[gi * NCLS + threadIdx.x] = lg[threadIdx.x] - m - logf(sum);
    }
}

// ---------------- launch ----------------

extern "C" void kernel_launch(void* const* d_in, const int* in_sizes, int n_in,
                              void* d_out, int out_size, void* d_ws, size_t ws_size,
                              hipStream_t stream) {
    const float* x = (const float*)d_in[0];
    const int* ei = (const int*)d_in[1];
    const int* src = ei;
    const int* dst = ei + NE;
    const int* batch = (const int*)d_in[2];
    const float* W1 = (const float*)d_in[3];
    const float* b1 = (const float*)d_in[4];
    const float* W2 = (const float*)d_in[5];
    const float* b2 = (const float*)d_in[6];
    const float* W3 = (const float*)d_in[7];
    const float* b3 = (const float*)d_in[8];
    const float* fc1w = (const float*)d_in[9];
    const float* fc1b = (const float*)d_in[10];
    const float* fc2w = (const float*)d_in[11];
    const float* fc2b = (const float*)d_in[12];
    const float* fc3w = (const float*)d_in[13];
    const float* fc3b = (const float*)d_in[14];
    float* out = (float*)d_out;

    char* p = (char*)d_ws;
    auto carve = [&](size_t bytes) {
        char* r = p;
        p += align_up(bytes, 256);
        return (void*)r;
    };
    float* A = (float*)carve((size_t)NN * HID * 4);
    float* B = (float*)carve((size_t)NN * HID * 4);
    float* O1 = (float*)carve((size_t)NN * HID * 4);
    float* O2 = (float*)carve((size_t)NN * HID * 4);
    float* deg = (float*)carve((size_t)NN * 4);
    float* dis = (float*)carve((size_t)NN * 4);
    float* wcsr = (float*)carve((size_t)NE * 4);
    int* cnt = (int*)carve((size_t)NN * 4);
    int* row_ptr = (int*)carve((size_t)(NN + 1) * 4);
    int* cursor = (int*)carve((size_t)NN * 4);
    int* col = (int*)carve((size_t)NE * 4);
    float* psum = (float*)carve((size_t)NG * HID * 4);
    float* pcnt = (float*)carve((size_t)NG * 4);
    float* g = (float*)carve((size_t)NG * HID * 4);
    float* f1 = (float*)carve((size_t)NG * 512 * 4);
    float* f2 = (float*)carve((size_t)NG * HID * 4);

    hipMemsetAsync(deg, 0, (size_t)NN * 4, stream);
    hipMemsetAsync(cnt, 0, (size_t)NN * 4, stream);
    hipMemsetAsync(psum, 0, (size_t)NG * HID * 4, stream);
    hipMemsetAsync(pcnt, 0, (size_t)NG * 4, stream);

    k_degcnt<<<(NE + 255) / 256, 256, 0, stream>>>(src, dst, deg, cnt);
    k_dis<<<(NN + 255) / 256, 256, 0, stream>>>(deg, dis);
    k_scan<<<1, 1024, 0, stream>>>(cnt, row_ptr, cursor);
    k_fill<<<(NE + 255) / 256, 256, 0, stream>>>(src, dst, dis, cursor, col, wcsr);

    dim3 mmg((NN + 63) / 64, HID / 64);

    // ---- layer 1: K=3, 128 -> 256, input x, output O1 ----
    k_mm<0, 0><<<mmg, 256, 0, stream>>>(x, W1, nullptr, O1, NN, FIN, HID);
    k_prop<0><<<NN, FIN, 0, stream>>>(row_ptr, col, wcsr, x, nullptr, B, FIN);
    k_mm<1, 0><<<mmg, 256, 0, stream>>>(B, W1 + (size_t)1 * FIN * HID, nullptr, O1, NN, FIN, HID);
    k_prop<1><<<NN, FIN, 0, stream>>>(row_ptr, col, wcsr, B, x, A, FIN);
    k_mm<1, 1><<<mmg, 256, 0, stream>>>(A, W1 + (size_t)2 * FIN * HID, b1, O1, NN, FIN, HID);

    // ---- layer 2: K=4, 256 -> 256, input O1, output O2 ----
    k_mm<0, 0><<<mmg, 256, 0, stream>>>(O1, W2, nullptr, O2, NN, HID, HID);
    k_prop<0><<<NN, HID, 0, stream>>>(row_ptr, col, wcsr, O1, nullptr, B, HID);
    k_mm<1, 0><<<mmg, 256, 0, stream>>>(B, W2 + (size_t)1 * HID * HID, nullptr, O2, NN, HID, HID);
    k_prop<1><<<NN, HID, 0, stream>>>(row_ptr, col, wcsr, B, O1, A, HID);
    k_mm<1, 0><<<mmg, 256, 0, stream>>>(A, W2 + (size_t)2 * HID * HID, nullptr, O2, NN, HID, HID);
    k_prop<1><<<NN, HID, 0, stream>>>(row_ptr, col, wcsr, A, B, B, HID);
    k_mm<1, 1><<<mmg, 256, 0, stream>>>(B, W2 + (size_t)3 * HID * HID, b2, O2, NN, HID, HID);

    // ---- layer 3: K=5, 256 -> 256, input O2, output O1 ----
    k_mm<0, 0><<<mmg, 256, 0, stream>>>(O2, W3, nullptr, O1, NN, HID, HID);
    k_prop<0><<<NN, HID, 0, stream>>>(row_ptr, col, wcsr, O2, nullptr, B, HID);
    k_mm<1, 0><<<mmg, 256, 0, stream>>>(B, W3 + (size_t)1 * HID * HID, nullptr, O1, NN, HID, HID);
    k_prop<1><<<NN, HID, 0, stream>>>(row_ptr, col, wcsr, B, O2, A, HID);
    k_mm<1, 0><<<mmg, 256, 0, stream>>>(A, W3 + (size_t)2 * HID * HID, nullptr, O1, NN, HID, HID);
    k_prop<1><<<NN, HID, 0, stream>>>(row_ptr, col, wcsr, A, B, B, HID);
    k_mm<1, 0><<<mmg, 256, 0, stream>>>(B, W3 + (size_t)3 * HID * HID, nullptr, O1, NN, HID, HID);
    k_prop<1><<<NN, HID, 0, stream>>>(row_ptr, col, wcsr, B, A, A, HID);
    k_mm<1, 1><<<mmg, 256, 0, stream>>>(A, W3 + (size_t)4 * HID * HID, b3, O1, NN, HID, HID);

    // ---- pool + MLP ----
    k_pool<<<(NN + 127) / 128, 256, 0, stream>>>(O1, batch, psum, pcnt);
    k_gdiv<<<(NG * HID) / 256, 256, 0, stream>>>(psum, pcnt, g);
    k_fc<1><<<dim3(NG, 2), 256, 0, stream>>>(g, fc1w, fc1b, f1, HID, 512);
    k_fc<1><<<dim3(NG, 1), 256, 0, stream>>>(f1, fc2w, fc2b, f2, 512, HID);
    k_fc3_lsm<<<NG, 256, 0, stream>>>(f2, fc3w, fc3b, out);
}

// Round 2
// 980.624 us; speedup vs baseline: 3.2427x; 3.2427x over previous
//
#include <hip/hip_runtime.h>
#include <cstdint>
#include <cstddef>

#define NN 50000
#define NE 800000
#define FIN 128
#define HID 256
#define NCLS 10
#define NG 64
#define NB 196          // ceil(NN/256)
#define LDT 1280        // Tbig row stride in elements (5 * 256)

typedef unsigned int uint;
typedef unsigned short ushort;
typedef __attribute__((ext_vector_type(8))) short short8;
typedef __attribute__((ext_vector_type(4))) float f32x4;

static inline size_t align_up(size_t v, size_t a) { return (v + a - 1) / a * a; }

__device__ __forceinline__ float bf2f(ushort u) {
    union { uint i; float f; } v; v.i = (uint)u << 16; return v.f;
}
__device__ __forceinline__ ushort f2bf(float f) {
    union { uint i; float f; } v; v.f = f;
    uint i = v.i;
    uint r = (i + 0x7fffu + ((i >> 16) & 1u)) >> 16;
    return (ushort)r;
}
__device__ __forceinline__ uint pack2(float a, float b) {
    return (uint)f2bf(a) | ((uint)f2bf(b) << 16);
}

// ---------------- graph preprocessing ----------------

__global__ void k_degcnt(const int* __restrict__ src, const int* __restrict__ dst,
                         int* __restrict__ ideg, int* __restrict__ cnt) {
    int e = blockIdx.x * 256 + threadIdx.x;
    if (e < NE) {
        atomicAdd(&ideg[src[e]], 1);
        atomicAdd(&cnt[dst[e]], 1);
    }
}

__global__ void k_dis(const int* __restrict__ ideg, float* __restrict__ dis) {
    int n = blockIdx.x * 256 + threadIdx.x;
    if (n < NN) {
        int d = ideg[n];
        dis[n] = (d > 0) ? rsqrtf((float)d) : 0.0f;
    }
}

// 3-phase exclusive scan of cnt -> row_ptr (+cursor copy)
__global__ void k_scan1(const int* __restrict__ cnt, int* __restrict__ rp,
                        int* __restrict__ bsum) {
    __shared__ int s[256];
    int i = blockIdx.x * 256 + threadIdx.x;
    int v = (i < NN) ? cnt[i] : 0;
    s[threadIdx.x] = v;
    __syncthreads();
    for (int off = 1; off < 256; off <<= 1) {
        int t = (threadIdx.x >= (unsigned)off) ? s[threadIdx.x - off] : 0;
        __syncthreads();
        s[threadIdx.x] += t;
        __syncthreads();
    }
    if (i < NN) rp[i] = s[threadIdx.x] - v;  // exclusive within block
    if (threadIdx.x == 255) bsum[blockIdx.x] = s[255];
}

__global__ void k_scan2(const int* __restrict__ bsum, int* __restrict__ boff) {
    __shared__ int s[256];
    int v = (threadIdx.x < NB) ? bsum[threadIdx.x] : 0;
    s[threadIdx.x] = v;
    __syncthreads();
    for (int off = 1; off < 256; off <<= 1) {
        int t = (threadIdx.x >= (unsigned)off) ? s[threadIdx.x - off] : 0;
        __syncthreads();
        s[threadIdx.x] += t;
        __syncthreads();
    }
    if (threadIdx.x < NB) boff[threadIdx.x] = s[threadIdx.x] - v;
}

__global__ void k_scan3(const int* __restrict__ boff, int* __restrict__ rp,
                        int* __restrict__ cur) {
    int i = blockIdx.x * 256 + threadIdx.x;
    if (i < NN) {
        int v = rp[i] + boff[blockIdx.x];
        rp[i] = v;
        cur[i] = v;
    }
    if (i == 0) rp[NN] = NE;
}

__global__ void k_fill(const int* __restrict__ src, const int* __restrict__ dst,
                       const float* __restrict__ dis, int* __restrict__ cursor,
                       int* __restrict__ col, float* __restrict__ wcsr) {
    int e = blockIdx.x * 256 + threadIdx.x;
    if (e < NE) {
        int s_ = src[e], d_ = dst[e];
        int pos = atomicAdd(&cursor[d_], 1);
        col[pos] = s_;
        wcsr[pos] = -dis[s_] * dis[d_];
    }
}

// ---------------- weight transpose + bf16 convert ----------------
// W [K][256] fp32 -> Wt [256][K] bf16
__global__ void k_wt(const float* __restrict__ W, ushort* __restrict__ Wt, int K) {
    int i = blockIdx.x * 256 + threadIdx.x;
    if (i < K * 256) {
        int k = i >> 8, n = i & 255;
        Wt[(size_t)n * K + k] = f2bf(W[i]);
    }
}

// ---------------- spread kernels (into Tbig slot 0) ----------------

__global__ void k_spread_x(const float* __restrict__ x, ushort* __restrict__ T) {
    int i = blockIdx.x * 256 + threadIdx.x;  // NN*64 threads, 2 floats each
    if (i < NN * 64) {
        int m = i >> 6, p = i & 63;
        const float* xp = x + (size_t)m * FIN + p * 2;
        uint* tp = (uint*)(T + (size_t)m * LDT) + p;
        *tp = pack2(xp[0], xp[1]);
    }
}

__global__ void k_spread_h(const ushort* __restrict__ h, ushort* __restrict__ T) {
    int i = blockIdx.x * 256 + threadIdx.x;  // NN*32 chunks of 16B
    if (i < NN * 32) {
        int m = i >> 5, c = i & 31;
        const uint4* sp = (const uint4*)(h + (size_t)m * HID) + c;
        uint4* dp = (uint4*)(T + (size_t)m * LDT) + c;
        *dp = *sp;
    }
}

// ---------------- sparse propagation (bf16, strided in Tbig) ----------------
// one wave (64 lanes) per node; 4 nodes per 256-thread block
// F==256 -> each lane handles uint2 (4 bf16); F==128 -> uint (2 bf16)
template <int FUSE, int F>
__global__ void k_prop(const int* __restrict__ rp, const int* __restrict__ col,
                       const float* __restrict__ w, const ushort* __restrict__ h,
                       const ushort* __restrict__ sub, ushort* __restrict__ out) {
    constexpr int NC = F / 128;  // uints per lane
    int d = blockIdx.x * 4 + (threadIdx.x >> 6);
    int t = threadIdx.x & 63;
    int beg = rp[d], end = rp[d + 1];
    float a[NC * 2] = {};
    int e = beg;
    for (; e + 1 < end; e += 2) {
        int s0 = col[e], s1 = col[e + 1];
        float w0 = w[e], w1 = w[e + 1];
        if (NC == 2) {
            uint2 v0 = *((const uint2*)(h + (size_t)s0 * LDT) + t);
            uint2 v1 = *((const uint2*)(h + (size_t)s1 * LDT) + t);
            a[0] += w0 * bf2f((ushort)v0.x); a[1] += w0 * bf2f((ushort)(v0.x >> 16));
            a[2] += w0 * bf2f((ushort)v0.y); a[3] += w0 * bf2f((ushort)(v0.y >> 16));
            a[0] += w1 * bf2f((ushort)v1.x); a[1] += w1 * bf2f((ushort)(v1.x >> 16));
            a[2] += w1 * bf2f((ushort)v1.y); a[3] += w1 * bf2f((ushort)(v1.y >> 16));
        } else {
            uint v0 = *((const uint*)(h + (size_t)s0 * LDT) + t);
            uint v1 = *((const uint*)(h + (size_t)s1 * LDT) + t);
            a[0] += w0 * bf2f((ushort)v0); a[1] += w0 * bf2f((ushort)(v0 >> 16));
            a[0] += w1 * bf2f((ushort)v1); a[1] += w1 * bf2f((ushort)(v1 >> 16));
        }
    }
    if (e < end) {
        int s0 = col[e];
        float w0 = w[e];
        if (NC == 2) {
            uint2 v0 = *((const uint2*)(h + (size_t)s0 * LDT) + t);
            a[0] += w0 * bf2f((ushort)v0.x); a[1] += w0 * bf2f((ushort)(v0.x >> 16));
            a[2] += w0 * bf2f((ushort)v0.y); a[3] += w0 * bf2f((ushort)(v0.y >> 16));
        } else {
            uint v0 = *((const uint*)(h + (size_t)s0 * LDT) + t);
            a[0] += w0 * bf2f((ushort)v0); a[1] += w0 * bf2f((ushort)(v0 >> 16));
        }
    }
    uint* op = (uint*)(out + (size_t)d * LDT) + t * NC;
    if (FUSE) {
        const uint* sp = (const uint*)(sub + (size_t)d * LDT) + t * NC;
#pragma unroll
        for (int c = 0; c < NC; ++c) {
            uint sv = sp[c];
            float r0 = 2.0f * a[2 * c] - bf2f((ushort)sv);
            float r1 = 2.0f * a[2 * c + 1] - bf2f((ushort)(sv >> 16));
            op[c] = pack2(r0, r1);
        }
    } else {
#pragma unroll
        for (int c = 0; c < NC; ++c) op[c] = pack2(a[2 * c], a[2 * c + 1]);
    }
}

// ---------------- MFMA matmul: H = relu(A[M x K] @ Wt^T + bias), bf16 out ----
// A row-major bf16 with stride lda; Wt [256][K] bf16 (pre-transposed weights)
__global__ __launch_bounds__(256) void k_mm_mfma(
    const ushort* __restrict__ A, int lda, int M, int K,
    const ushort* __restrict__ Wt, const float* __restrict__ bias,
    ushort* __restrict__ H) {
    __shared__ ushort As[128 * 32];
    __shared__ ushort Bs[128 * 32];
    int tid = threadIdx.x;
    int lane = tid & 63, w = tid >> 6;
    int wm = w >> 1, wn = w & 1;
    int rowBase = blockIdx.x * 128;
    int colBase = blockIdx.y * 128;
    f32x4 acc[4][4];
#pragma unroll
    for (int i = 0; i < 4; ++i)
#pragma unroll
        for (int j = 0; j < 4; ++j) acc[i][j] = (f32x4){0.f, 0.f, 0.f, 0.f};

    int srow = lane >> 2;  // 0..15 within 16-row segment
    int c16 = lane & 3;    // 16B chunk within 64B row

    for (int k0 = 0; k0 < K; k0 += 32) {
        // stage A tile [128][32] bf16, XOR chunk swizzle s(r) = (r>>1)&3
#pragma unroll
        for (int q = 0; q < 2; ++q) {
            int seg = w * 2 + q;
            int r = seg * 16 + srow;
            int cs = c16 ^ ((r >> 1) & 3);
            int grow = rowBase + r;
            if (grow > M - 1) grow = M - 1;
            const ushort* gp = A + (size_t)grow * lda + k0 + cs * 8;
            __builtin_amdgcn_global_load_lds(
                (const __attribute__((address_space(1))) void*)gp,
                (__attribute__((address_space(3))) void*)((char*)As + seg * 1024),
                16, 0, 0);
        }
        // stage B tile: rows = output cols, same swizzle
#pragma unroll
        for (int q = 0; q < 2; ++q) {
            int seg = w * 2 + q;
            int r = seg * 16 + srow;
            int cs = c16 ^ ((r >> 1) & 3);
            const ushort* gp = Wt + (size_t)(colBase + r) * K + k0 + cs * 8;
            __builtin_amdgcn_global_load_lds(
                (const __attribute__((address_space(1))) void*)gp,
                (__attribute__((address_space(3))) void*)((char*)Bs + seg * 1024),
                16, 0, 0);
        }
        __syncthreads();
        short8 af[4], bf[4];
#pragma unroll
        for (int mi = 0; mi < 4; ++mi) {
            int r = wm * 64 + mi * 16 + (lane & 15);
            int j = (lane >> 4) ^ ((r >> 1) & 3);
            af[mi] = *(const short8*)((const char*)As + r * 64 + j * 16);
        }
#pragma unroll
        for (int ni = 0; ni < 4; ++ni) {
            int r = wn * 64 + ni * 16 + (lane & 15);
            int j = (lane >> 4) ^ ((r >> 1) & 3);
            bf[ni] = *(const short8*)((const char*)Bs + r * 64 + j * 16);
        }
#pragma unroll
        for (int mi = 0; mi < 4; ++mi)
#pragma unroll
            for (int ni = 0; ni < 4; ++ni)
                acc[mi][ni] = __builtin_amdgcn_mfma_f32_16x16x32_bf16(
                    af[mi], bf[ni], acc[mi][ni], 0, 0, 0);
        __syncthreads();
    }
    // epilogue: bias + relu -> bf16
    int lg = lane >> 4;
    float bv[4];
#pragma unroll
    for (int ni = 0; ni < 4; ++ni)
        bv[ni] = bias[colBase + wn * 64 + ni * 16 + (lane & 15)];
#pragma unroll
    for (int mi = 0; mi < 4; ++mi) {
#pragma unroll
        for (int r = 0; r < 4; ++r) {
            int row = rowBase + wm * 64 + mi * 16 + lg * 4 + r;
            if (row >= M) continue;
#pragma unroll
            for (int ni = 0; ni < 4; ++ni) {
                int colL = colBase + wn * 64 + ni * 16 + (lane & 15);
                float v = acc[mi][ni][r] + bv[ni];
                v = fmaxf(v, 0.0f);
                H[(size_t)row * HID + colL] = f2bf(v);
            }
        }
    }
}

// ---------------- pooling (bf16 input) ----------------

__global__ void k_pool(const ushort* __restrict__ h, const int* __restrict__ batch,
                       float* __restrict__ sums, float* __restrict__ cnts) {
    int f = threadIdx.x;  // 256
    int n0 = blockIdx.x * 128;
    if (n0 >= NN) return;
    int nEnd = n0 + 128 < NN ? n0 + 128 : NN;
    int cur = batch[n0];
    float acc = 0.0f, c = 0.0f;
    for (int n = n0; n < nEnd; ++n) {
        int b = batch[n];
        if (b != cur) {
            atomicAdd(&sums[cur * HID + f], acc);
            if (f == 0) atomicAdd(&cnts[cur], c);
            acc = 0.0f; c = 0.0f; cur = b;
        }
        acc += bf2f(h[(size_t)n * HID + f]);
        c += 1.0f;
    }
    atomicAdd(&sums[cur * HID + f], acc);
    if (f == 0) atomicAdd(&cnts[cur], c);
}

__global__ void k_gdiv(const float* __restrict__ sums, const float* __restrict__ cnts,
                       float* __restrict__ g) {
    int i = blockIdx.x * 256 + threadIdx.x;  // NG*HID
    int b = i >> 8;
    g[i] = sums[i] / fmaxf(cnts[b], 1.0f);
}

// ---------------- MLP (fp32, tiny) ----------------

template <int RELU>
__global__ void k_fc(const float* __restrict__ in, const float* __restrict__ W,
                     const float* __restrict__ bias, float* __restrict__ out,
                     int K, int Nc) {
    __shared__ float s[512];
    int gi = blockIdx.x;
    for (int i = threadIdx.x; i < K; i += blockDim.x) s[i] = in[gi * K + i];
    __syncthreads();
    int c = blockIdx.y * blockDim.x + threadIdx.x;
    if (c < Nc) {
        float acc = bias[c];
        for (int k = 0; k < K; ++k) acc += s[k] * W[k * Nc + c];
        out[gi * Nc + c] = RELU ? fmaxf(acc, 0.0f) : acc;
    }
}

__global__ void k_fc3_lsm(const float* __restrict__ in, const float* __restrict__ W,
                          const float* __restrict__ b, float* __restrict__ out) {
    __shared__ float s[HID];
    __shared__ float lg[NCLS];
    int gi = blockIdx.x;
    s[threadIdx.x] = in[gi * HID + threadIdx.x];  // blockDim=256
    __syncthreads();
    if (threadIdx.x < NCLS) {
        float acc = b[threadIdx.x];
        for (int k = 0; k < HID; ++k) acc += s[k] * W[k * NCLS + threadIdx.x];
        lg[threadIdx.x] = acc;
    }
    __syncthreads();
    if (threadIdx.x < NCLS) {
        float m = -1e30f;
        for (int c = 0; c < NCLS; ++c) m = fmaxf(m, lg[c]);
        float sum = 0.0f;
        for (int c = 0; c < NCLS; ++c) sum += expf(lg[c] - m);
        out[gi * NCLS + threadIdx.x] = lg[threadIdx.x] - m - logf(sum);
    }
}

// ---------------- launch ----------------

extern "C" void kernel_launch(void* const* d_in, const int* in_sizes, int n_in,
                              void* d_out, int out_size, void* d_ws, size_t ws_size,
                              hipStream_t stream) {
    const float* x = (const float*)d_in[0];
    const int* ei = (const int*)d_in[1];
    const int* src = ei;
    const int* dst = ei + NE;
    const int* batch = (const int*)d_in[2];
    const float* W1 = (const float*)d_in[3];
    const float* b1 = (const float*)d_in[4];
    const float* W2 = (const float*)d_in[5];
    const float* b2 = (const float*)d_in[6];
    const float* W3 = (const float*)d_in[7];
    const float* b3 = (const float*)d_in[8];
    const float* fc1w = (const float*)d_in[9];
    const float* fc1b = (const float*)d_in[10];
    const float* fc2w = (const float*)d_in[11];
    const float* fc2b = (const float*)d_in[12];
    const float* fc3w = (const float*)d_in[13];
    const float* fc3b = (const float*)d_in[14];
    float* out = (float*)d_out;

    char* p = (char*)d_ws;
    auto carve = [&](size_t bytes) {
        char* r = p;
        p += align_up(bytes, 256);
        return (void*)r;
    };
    ushort* Tbig = (ushort*)carve((size_t)NN * LDT * 2);
    ushort* hA = (ushort*)carve((size_t)NN * HID * 2);
    ushort* hB = (ushort*)carve((size_t)NN * HID * 2);
    ushort* Wt1 = (ushort*)carve((size_t)HID * 384 * 2);
    ushort* Wt2 = (ushort*)carve((size_t)HID * 1024 * 2);
    ushort* Wt3 = (ushort*)carve((size_t)HID * 1280 * 2);
    int* ideg = (int*)carve((size_t)NN * 4);
    int* cnt = (int*)carve((size_t)NN * 4);
    float* dis = (float*)carve((size_t)NN * 4);
    int* row_ptr = (int*)carve((size_t)(NN + 1) * 4);
    int* cursor = (int*)carve((size_t)NN * 4);
    int* col = (int*)carve((size_t)NE * 4);
    float* wcsr = (float*)carve((size_t)NE * 4);
    int* bsum = (int*)carve((size_t)NB * 4);
    int* boff = (int*)carve((size_t)NB * 4);
    float* psum = (float*)carve((size_t)NG * HID * 4);
    float* pcnt = (float*)carve((size_t)NG * 4);
    float* g = (float*)carve((size_t)NG * HID * 4);
    float* f1 = (float*)carve((size_t)NG * 512 * 4);
    float* f2 = (float*)carve((size_t)NG * HID * 4);

    hipMemsetAsync(ideg, 0, (size_t)NN * 4, stream);
    hipMemsetAsync(cnt, 0, (size_t)NN * 4, stream);
    hipMemsetAsync(psum, 0, (size_t)NG * HID * 4, stream);
    hipMemsetAsync(pcnt, 0, (size_t)NG * 4, stream);

    // graph preprocessing
    k_degcnt<<<(NE + 255) / 256, 256, 0, stream>>>(src, dst, ideg, cnt);
    k_dis<<<(NN + 255) / 256, 256, 0, stream>>>(ideg, dis);
    k_scan1<<<NB, 256, 0, stream>>>(cnt, row_ptr, bsum);
    k_scan2<<<1, 256, 0, stream>>>(bsum, boff);
    k_scan3<<<NB, 256, 0, stream>>>(boff, row_ptr, cursor);
    k_fill<<<(NE + 255) / 256, 256, 0, stream>>>(src, dst, dis, cursor, col, wcsr);

    // weight transpose/convert
    k_wt<<<(384 * 256 + 255) / 256, 256, 0, stream>>>(W1, Wt1, 384);
    k_wt<<<(1024 * 256 + 255) / 256, 256, 0, stream>>>(W2, Wt2, 1024);
    k_wt<<<(1280 * 256 + 255) / 256, 256, 0, stream>>>(W3, Wt3, 1280);

    dim3 mmg((NN + 127) / 128, 2);

    // ---- layer 1 (F=128, K=3 hops, K_eff=384) ----
    k_spread_x<<<(NN * 64 + 255) / 256, 256, 0, stream>>>(x, Tbig);
    k_prop<0, 128><<<NN / 4, 256, 0, stream>>>(row_ptr, col, wcsr, Tbig + 0, nullptr, Tbig + 128);
    k_prop<1, 128><<<NN / 4, 256, 0, stream>>>(row_ptr, col, wcsr, Tbig + 128, Tbig + 0, Tbig + 256);
    k_mm_mfma<<<mmg, 256, 0, stream>>>(Tbig, LDT, NN, 384, Wt1, b1, hA);

    // ---- layer 2 (F=256, K=4 hops, K_eff=1024) ----
    k_spread_h<<<(NN * 32 + 255) / 256, 256, 0, stream>>>(hA, Tbig);
    k_prop<0, 256><<<NN / 4, 256, 0, stream>>>(row_ptr, col, wcsr, Tbig + 0, nullptr, Tbig + 256);
    k_prop<1, 256><<<NN / 4, 256, 0, stream>>>(row_ptr, col, wcsr, Tbig + 256, Tbig + 0, Tbig + 512);
    k_prop<1, 256><<<NN / 4, 256, 0, stream>>>(row_ptr, col, wcsr, Tbig + 512, Tbig + 256, Tbig + 768);
    k_mm_mfma<<<mmg, 256, 0, stream>>>(Tbig, LDT, NN, 1024, Wt2, b2, hB);

    // ---- layer 3 (F=256, K=5 hops, K_eff=1280) ----
    k_spread_h<<<(NN * 32 + 255) / 256, 256, 0, stream>>>(hB, Tbig);
    k_prop<0, 256><<<NN / 4, 256, 0, stream>>>(row_ptr, col, wcsr, Tbig + 0, nullptr, Tbig + 256);
    k_prop<1, 256><<<NN / 4, 256, 0, stream>>>(row_ptr, col, wcsr, Tbig + 256, Tbig + 0, Tbig + 512);
    k_prop<1, 256><<<NN / 4, 256, 0, stream>>>(row_ptr, col, wcsr, Tbig + 512, Tbig + 256, Tbig + 768);
    k_prop<1, 256><<<NN / 4, 256, 0, stream>>>(row_ptr, col, wcsr, Tbig + 768, Tbig + 512, Tbig + 1024);
    k_mm_mfma<<<mmg, 256, 0, stream>>>(Tbig, LDT, NN, 1280, Wt3, b3, hA);

    // ---- pool + MLP ----
    k_pool<<<(NN + 127) / 128, 256, 0, stream>>>(hA, batch, psum, pcnt);
    k_gdiv<<<(NG * HID) / 256, 256, 0, stream>>>(psum, pcnt, g);
    k_fc<1><<<dim3(NG, 2), 256, 0, stream>>>(g, fc1w, fc1b, f1, HID, 512);
    k_fc<1><<<dim3(NG, 1), 256, 0, stream>>>(f1, fc2w, fc2b, f2, 512, HID);
    k_fc3_lsm<<<NG, 256, 0, stream>>>(f2, fc3w, fc3b, out);
}